// Round 12
// baseline (38328.207 us; speedup 1.0000x reference)
//
#include <hip/hip_runtime.h>
#include <hip/hip_bf16.h>
#include <math.h>
#include <stdint.h>

// Seq2Seq LAS model. B=32, T=1664, F_IN=80, H_ENC=256, KV=128, D_DEC=512,
// EMB=256, VOCAB=30, L=200.
// R18: release-publish (R17 + wave0-release flag stores).
//  - In pyr / l0_s4 / attend the cross-WG producers (h, ctx) are wave 0
//    only (tid<64). vmcnt is a PER-WAVE counter covering all 64 lanes, so
//    a RELEASE agent-scope flag store by tid 0 drains wave 0's h-stores
//    without a WG-wide __syncthreads. Removes one 4-wave barrier per step
//    from the publish path (pyr 1456 + l0 1664 + attend 200 steps).
//  - cell1/cell2 keep the barrier: their H1/H2 stores span all 4 waves.
//  - Consumer ordering unchanged: poll + trailing __syncthreads.
//  - WAR re-check: every shared LDS buffer's next write sits behind a
//    later all-wave sync (S0/S1/dec_poll); prior reads precede S2/S5.
// pyr (R8 body), l0 (R13), decoder (R7+R17 early-FCT), GEMMs unchanged.

#define DEV __device__ __forceinline__

#define FLAG_STRIDE 16  // dwords; one flag per 64B line

DEV float sigmf(float x) { return 1.0f / (1.0f + __expf(-x)); }
DEV float tanh_(float x) { return 1.0f - 2.0f / (__expf(2.0f * x) + 1.0f); }

struct __align__(8) bf4 { __hip_bfloat16 a, b, c, d; };

DEV float4 ld4g(const float* p) { return *(const float4*)p; }
DEV float4 ld4g(const __hip_bfloat16* p) {
    bf4 v = *(const bf4*)p;
    return make_float4(__bfloat162float(v.a), __bfloat162float(v.b),
                       __bfloat162float(v.c), __bfloat162float(v.d));
}
DEV void st1g(float* p, float v) { *p = v; }
DEV void st1g(__hip_bfloat16* p, float v) { *p = __float2bfloat16(v); }

DEV void st_coh(float* p, float v) {
    __hip_atomic_store(p, v, __ATOMIC_RELAXED, __HIP_MEMORY_SCOPE_AGENT);
}
DEV unsigned long long ld_coh64(const unsigned long long* p) {
    return __hip_atomic_load(p, __ATOMIC_RELAXED, __HIP_MEMORY_SCOPE_AGENT);
}
DEV float ld_coh32(const float* p) {
    return __hip_atomic_load(p, __ATOMIC_RELAXED, __HIP_MEMORY_SCOPE_AGENT);
}
DEV void st_coh64(unsigned long long* p, unsigned long long v) {
    __hip_atomic_store(p, v, __ATOMIC_RELAXED, __HIP_MEMORY_SCOPE_AGENT);
}
// release publish: emits s_waitcnt vmcnt(0) draining the PUBLISHING WAVE's
// outstanding stores (all 64 lanes share the wave's vmcnt), then the store.
DEV void pub_rel(unsigned* p, unsigned v) {
    __hip_atomic_store(p, v, __ATOMIC_RELEASE, __HIP_MEMORY_SCOPE_AGENT);
}

// ---------------------------------------------------------------------------
// Weight transpose for split-4 l0: WT5[dir][g][kc][tid][j] with
// row(tid) = (tid>>6)*256 + g*64 + (tid&63), k = kc*4+j:
//   k<256 -> Whh[row][k]; 256<=k<336 -> Wih[row][k-256]; else 0 (pad).
// Total 2*4*88*1024 = 720896 floats.
// ---------------------------------------------------------------------------
__global__ void wt5_prep(const float* __restrict__ whh_f, const float* __restrict__ whh_b,
                         const float* __restrict__ wih_f, const float* __restrict__ wih_b,
                         float* __restrict__ WT5)
{
    int idx = blockIdx.x * 256 + threadIdx.x;
    if (idx >= 720896) return;
    int j = idx & 3, tid = (idx >> 2) & 255, kc = (idx >> 10) % 88, dg = idx / 90112;
    int dir = dg >> 2, g = dg & 3;
    int row = ((tid >> 6) << 8) + g * 64 + (tid & 63);
    int k = kc * 4 + j;
    const float* Whh = dir ? whh_b : whh_f;
    const float* Wih = dir ? wih_b : wih_f;
    float v = 0.f;
    if (k < 256) v = Whh[row * 256 + k];
    else if (k < 336) v = Wih[row * 80 + (k - 256)];
    WT5[idx] = v;
}

// ---------------------------------------------------------------------------
// Encoder layer 0, split-4 + register-resident weights (R13). grid 256:
// g = blk>>6, grp = blk&63, dir = grp>>5, b = grp&31. 256 threads: thread =
// gate q=tid>>6 of unit u = g*64+(tid&63). Weights (84 float4/thread) live
// in VGPRs across all 1664 steps. Per step: poll 4 group flags -> 1KB h
// reload -> K=336 register dot -> gates -> 64-unit h slice publish
// (wave0 RELEASE, no trailing barrier).
// HBUF layout: [grp][par][256] floats. Flags: [grp*4+g].
// ---------------------------------------------------------------------------
template <typename ST>
__global__ __launch_bounds__(256, 1) void lstm_l0_s4(
    const float* __restrict__ x,        // [32][1664][80]
    const float* __restrict__ WT5,      // [2][4][88][256][4]
    const float* __restrict__ bias_f, const float* __restrict__ bias_b,
    ST* __restrict__ out,               // [32][1664][512]
    float* __restrict__ hbuf, unsigned* __restrict__ flags)
{
    const int T = 1664;
    __shared__ __align__(16) float hx[336];  // 0..255 h (k-major), 256..335 x_t
    __shared__ float gs[256];

    const int tid = threadIdx.x;
    const int g = blockIdx.x >> 6;
    const int grp = blockIdx.x & 63;
    const int dir = grp >> 5;
    const int b = grp & 31;

    const float* wp = WT5 + (size_t)(dir * 4 + g) * 90112 + tid * 4;
    const int row = ((tid >> 6) << 8) + g * 64 + (tid & 63);
    const float bias_r = (dir ? bias_b : bias_f)[row];
    float c_reg = 0.f;  // valid for tid<64: unit g*64+tid

    unsigned* gflags = flags + grp * 4 * FLAG_STRIDE;
    float* hb = hbuf + grp * 512;  // [2][256]

    // ---- register-resident weights: 84 float4 = 336 VGPRs (1 wave/SIMD) ----
    float4 wreg[84];
#pragma unroll
    for (int kc = 0; kc < 84; kc++)
        wreg[kc] = *(const float4*)(wp + (size_t)kc * 1024);

    // x prefetch for t=0
    float4 xv = make_float4(0.f, 0.f, 0.f, 0.f);
    if (tid < 20) {
        int t0 = dir ? (T - 1) : 0;
        xv = *(const float4*)&x[((size_t)b * T + t0) * 80 + tid * 4];
    }

    for (int t = 0; t < T; t++) {
        const int par = t & 1;
        const int t_act = dir ? (T - 1 - t) : t;

        // x-stage: safe vs prior step's hx readers (all reads precede S2,
        // which every wave passed before wave0 could loop here).
        if (tid < 20) *(float4*)&hx[256 + tid * 4] = xv;
        if (tid < 20 && t + 1 < T) {  // prefetch next step's x
            int tn = dir ? (T - 2 - t) : (t + 1);
            xv = *(const float4*)&x[((size_t)b * T + tn) * 80 + tid * 4];
        }

        // ---- wait for all 4 group slices of h(t-1) ----
        if (tid < 4) {
            int guard = 0;
            while (__hip_atomic_load(&gflags[tid * FLAG_STRIDE], __ATOMIC_RELAXED,
                                     __HIP_MEMORY_SCOPE_AGENT) < (unsigned)t) {
                __builtin_amdgcn_s_sleep(1);
                if (++guard > (1 << 16)) break;  // anti-hang
            }
        }
        __syncthreads();  // S0: flags seen by whole WG

        // ---- coherent h reload (1KB, k-major: no transpose) ----
        if (tid < 128) {
            unsigned long long v =
                ld_coh64((const unsigned long long*)(hb + par * 256) + tid);
            hx[2 * tid] = __uint_as_float((unsigned)v);
            hx[2 * tid + 1] = __uint_as_float((unsigned)(v >> 32));
        }
        __syncthreads();  // S1: h + x visible

        // ---- K=336 dot from register weights; 4 accumulators ----
        float a0 = bias_r, a1 = 0.f, a2 = 0.f, a3 = 0.f;
#pragma unroll
        for (int kc = 0; kc < 84; kc += 4) {
            float4 w0 = wreg[kc + 0], w1 = wreg[kc + 1];
            float4 w2 = wreg[kc + 2], w3 = wreg[kc + 3];
            float4 h0 = *(const float4*)&hx[(kc + 0) * 4];
            float4 h1 = *(const float4*)&hx[(kc + 1) * 4];
            float4 h2 = *(const float4*)&hx[(kc + 2) * 4];
            float4 h3 = *(const float4*)&hx[(kc + 3) * 4];
            a0 = fmaf(w0.x, h0.x, fmaf(w0.y, h0.y, fmaf(w0.z, h0.z, fmaf(w0.w, h0.w, a0))));
            a1 = fmaf(w1.x, h1.x, fmaf(w1.y, h1.y, fmaf(w1.z, h1.z, fmaf(w1.w, h1.w, a1))));
            a2 = fmaf(w2.x, h2.x, fmaf(w2.y, h2.y, fmaf(w2.z, h2.z, fmaf(w2.w, h2.w, a2))));
            a3 = fmaf(w3.x, h3.x, fmaf(w3.y, h3.y, fmaf(w3.z, h3.z, fmaf(w3.w, h3.w, a3))));
        }
        gs[tid] = (a0 + a1) + (a2 + a3);
        __syncthreads();  // S2: gates ready; all dot-reads of hx done

        if (tid < 64) {
            float gi = gs[tid], gf = gs[64 + tid];
            float gg = gs[128 + tid], go = gs[192 + tid];
            float ci = sigmf(gi), cf = sigmf(gf), cg = tanh_(gg), co = sigmf(go);
            c_reg = cf * c_reg + ci * cg;
            float hval = co * tanh_(c_reg);
            // 64 lanes (wave 0) -> 256B contiguous slice of next-parity h
            st_coh(&hb[(par ^ 1) * 256 + g * 64 + tid], hval);
            st1g(&out[((size_t)b * T + t_act) * 512 + dir * 256 + g * 64 + tid], hval);
        }
        // RELEASE publish by tid 0 (wave 0): vmcnt(0) drains wave 0's
        // h-stores above; no WG barrier needed (stores are wave0-only).
        if (tid == 0)
            pub_rel(&gflags[g * FLAG_STRIDE], (unsigned)(t + 1));
        // next-step hx/gs writes ordered by next S0/S1.
    }
}

// ---------------------------------------------------------------------------
// Pyramid layer (persistent, R8 body + release publish). K = 1280 = 256 h
// (resident hsh, swizzled) + 4 in-groups of 256 (ping-pong is[2]).
// in-group g: row 2t+(g>>1), cols (g&1)*256..+255.
// ---------------------------------------------------------------------------
template <typename ST>
__global__ __launch_bounds__(256, 1) void lstm_pyr(
    const ST* __restrict__ in,          // [32][2*Tn][512]
    const float* __restrict__ whh_f, const float* __restrict__ whh_b,  // [1024][256]
    const float* __restrict__ wih_f, const float* __restrict__ wih_b,  // [1024][1024]
    const float* __restrict__ bias_f, const float* __restrict__ bias_b,
    ST* __restrict__ out,               // [32][Tn][512]
    float* __restrict__ hbuf, unsigned* __restrict__ flags, int Tn)
{
    const int RS = 260;  // row stride (4-aligned)
    __shared__ __align__(16) float hsh[32 * 260];
    __shared__ __align__(16) float is[2][32 * 260];
    __shared__ float pb[4][32][9];

    const int tid = threadIdx.x;
    const int dir = blockIdx.x >> 7;
    const int w = blockIdx.x & 127;
    const int wave = tid >> 6, lane = tid & 63;
    const int cl = lane & 7;
    const int ksub = lane >> 3;
    const int slot = (wave * 8 + ksub) * 4;
    const int col = (cl >> 1) * 256 + w * 2 + (cl & 1);
    const int Tprev = 2 * Tn;

    const float* Whh = dir ? whh_b : whh_f;
    const float* Wih = dir ? wih_b : wih_f;
    const float* bias = dir ? bias_b : bias_f;

    float4 wreg[10];
#pragma unroll
    for (int c = 0; c < 10; c++) {
        int k = c * 128 + slot;
        wreg[c] = (k < 256)
            ? *(const float4*)&Whh[(size_t)col * 256 + k]
            : *(const float4*)&Wih[(size_t)col * 1024 + (k - 256)];
    }

    const int sb = tid >> 3, q7 = tid & 7;  // in-staging role (lane-contiguous)
    const int qb = tid >> 1, qj = tid & 1;
    float bias_g[4];
#pragma unroll
    for (int g = 0; g < 4; g++) bias_g[g] = bias[g * 256 + w * 2 + (tid & 1)];
    float c_reg = 0.f;

    unsigned* myflags = flags + dir * 128 * FLAG_STRIDE;
    float* hb_base = hbuf + dir * 2 * 8192;

    for (int t = 0; t < Tn; t++) {
        const int par = t & 1;
        const int t_act = dir ? (Tn - 1 - t) : t;
        const unsigned long long* h64 =
            (const unsigned long long*)(hb_base + par * 8192);

        float acc[32];
#pragma unroll
        for (int b = 0; b < 32; b++) acc[b] = 0.f;

        // helper: load in-group g into registers (cols q7*4 + i*32: 8-lane
        // groups read/write contiguous 128B segments -> conflict-free)
        float4 gbuf[8];
        auto load_grp = [&](int g) {
            int r = 2 * t_act + (g >> 1);
            int cb = (g & 1) * 256;
            const ST* src = &in[((size_t)sb * Tprev + r) * 512 + cb + q7 * 4];
#pragma unroll
            for (int i = 0; i < 8; i++) gbuf[i] = ld4g(src + i * 32);
        };
        auto commit_grp = [&](int buf) {
#pragma unroll
            for (int i = 0; i < 8; i++)
                *(float4*)&is[buf][sb * RS + q7 * 4 + i * 32] = gbuf[i];
        };
        auto dot2 = [&](const float* base, int wi) {
#pragma unroll
            for (int cc = 0; cc < 2; cc++) {
                float4 wv = wreg[wi + cc];
                const float* src = base + cc * 128 + slot;
#pragma unroll
                for (int b = 0; b < 32; b++) {
                    float4 hv = *(const float4*)&src[b * RS];
                    acc[b] = fmaf(hv.x, wv.x, fmaf(hv.y, wv.y, fmaf(hv.z, wv.z, fmaf(hv.w, wv.w, acc[b]))));
                }
            }
        };
        auto dot2s = [&]() {  // h chunks from hsh (swizzled rows)
#pragma unroll
            for (int cc = 0; cc < 2; cc++) {
                float4 wv = wreg[cc];
                const int kb = cc * 128 + slot;
#pragma unroll
                for (int b = 0; b < 32; b++) {
                    float4 hv = *(const float4*)&hsh[b * RS + (kb ^ (((b >> 1) & 7) << 2))];
                    acc[b] = fmaf(hv.x, wv.x, fmaf(hv.y, wv.y, fmaf(hv.z, wv.z, fmaf(hv.w, wv.w, acc[b]))));
                }
            }
        };

        // ---- coherent wide h reload + group 0 ----
        unsigned long long hv64[16];
#pragma unroll
        for (int j = 0; j < 16; j++)
            hv64[j] = ld_coh64(&h64[tid + j * 256]);
        load_grp(0);
#pragma unroll
        for (int j = 0; j < 16; j++) {
            int q = tid + j * 256;
            int u = q >> 4, b0 = (q & 15) * 2;
            int uc = u ^ ((q & 7) << 2);
            hsh[b0 * RS + uc] = __uint_as_float((unsigned)hv64[j]);
            hsh[(b0 + 1) * RS + uc] = __uint_as_float((unsigned)(hv64[j] >> 32));
        }
        commit_grp(0);  // -> is[0]
        __syncthreads();  // S1

        load_grp(1);
        dot2s();                      // h chunks c0,c1 (swizzled hsh)
        dot2(&is[0][0], 2);           // c2,c3
        commit_grp(1);  // -> is[1]
        __syncthreads();  // S2

        load_grp(2);
        dot2(&is[1][0], 4);           // c4,c5
        commit_grp(0);  // -> is[0]
        __syncthreads();  // S3

        load_grp(3);
        dot2(&is[0][0], 6);           // c6,c7
        commit_grp(1);  // -> is[1]
        __syncthreads();  // S4

        dot2(&is[1][0], 8);           // c8,c9

#pragma unroll
        for (int b = 0; b < 32; b++) {
            acc[b] += __shfl_xor(acc[b], 8, 64);
            acc[b] += __shfl_xor(acc[b], 16, 64);
            acc[b] += __shfl_xor(acc[b], 32, 64);
        }
#pragma unroll
        for (int i = 0; i < 4; i++)
            pb[wave][ksub * 4 + i][cl] = acc[ksub * 4 + i];
        __syncthreads();  // S5

        if (tid < 64) {
            float ga[4];
#pragma unroll
            for (int gg = 0; gg < 4; gg++) {
                float s = bias_g[gg];
#pragma unroll
                for (int v = 0; v < 4; v++) s += pb[v][qb][gg * 2 + qj];
                ga[gg] = s;
            }
            float ci = sigmf(ga[0]), cf = sigmf(ga[1]);
            float cg = tanh_(ga[2]), co = sigmf(ga[3]);
            c_reg = cf * c_reg + ci * cg;
            float hval = co * tanh_(c_reg);
            // wave 0 only -> release below drains these
            st_coh(&hb_base[(par ^ 1) * 8192 + (w * 2 + qj) * 32 + qb], hval);
            st1g(&out[((size_t)qb * Tn + t_act) * 512 + dir * 256 + w * 2 + qj], hval);
        }

        // RELEASE publish by tid 0 (wave 0): drains wave 0's h-stores; waves
        // 1-3 proceed straight to the poll (no pre-publish barrier).
        if (tid == 0)
            pub_rel(&myflags[w * FLAG_STRIDE], (unsigned)(t + 1));
        if (tid < 128) {
            int guard = 0;
            while (__hip_atomic_load(&myflags[tid * FLAG_STRIDE], __ATOMIC_RELAXED,
                                     __HIP_MEMORY_SCOPE_AGENT) < (unsigned)(t + 1)) {
                __builtin_amdgcn_s_sleep(1);
                if (++guard > (1 << 15)) break;  // anti-hang
            }
        }
        __syncthreads();  // poll convergence; orders next-step LDS writes
    }
}

// ---------------------------------------------------------------------------
// C[M][N] = A[M][K] @ W[N][K]^T + bias  (fp32, 128x128 tiles, 8x8/thread)
// ---------------------------------------------------------------------------
__global__ __launch_bounds__(256) void gemm_bt(
    const float* __restrict__ A, const float* __restrict__ W,
    const float* __restrict__ bias, float* __restrict__ C,
    int M, int N, int K, int ldw)
{
    __shared__ __align__(16) float As[16][128];
    __shared__ __align__(16) float Ws[16][128];
    int tid = threadIdx.x;
    int m0 = blockIdx.x * 128, n0 = blockIdx.y * 128;
    int tx = tid & 15, ty = tid >> 4;

    float acc[8][8];
#pragma unroll
    for (int i = 0; i < 8; i++)
#pragma unroll
        for (int j = 0; j < 8; j++) acc[i][j] = 0.f;

    for (int kb = 0; kb < K; kb += 16) {
#pragma unroll
        for (int l = 0; l < 2; l++) {
            int idx = tid + l * 256;
            int row = idx >> 2, kq = (idx & 3) * 4;
            float4 v = make_float4(0.f, 0.f, 0.f, 0.f);
            if (m0 + row < M)
                v = *(const float4*)&A[(size_t)(m0 + row) * K + kb + kq];
            As[kq + 0][row] = v.x; As[kq + 1][row] = v.y;
            As[kq + 2][row] = v.z; As[kq + 3][row] = v.w;
        }
#pragma unroll
        for (int l = 0; l < 2; l++) {
            int idx = tid + l * 256;
            int row = idx >> 2, kq = (idx & 3) * 4;
            float4 v = *(const float4*)&W[(size_t)(n0 + row) * ldw + kb + kq];
            Ws[kq + 0][row] = v.x; Ws[kq + 1][row] = v.y;
            Ws[kq + 2][row] = v.z; Ws[kq + 3][row] = v.w;
        }
        __syncthreads();
#pragma unroll
        for (int k = 0; k < 16; k++) {
            float a[8], b[8];
            *(float4*)&a[0] = *(const float4*)&As[k][ty * 8];
            *(float4*)&a[4] = *(const float4*)&As[k][ty * 8 + 4];
            *(float4*)&b[0] = *(const float4*)&Ws[k][tx * 8];
            *(float4*)&b[4] = *(const float4*)&Ws[k][tx * 8 + 4];
#pragma unroll
            for (int i = 0; i < 8; i++)
#pragma unroll
                for (int j = 0; j < 8; j++)
                    acc[i][j] = fmaf(a[i], b[j], acc[i][j]);
        }
        __syncthreads();
    }
#pragma unroll
    for (int i = 0; i < 8; i++) {
        int m = m0 + ty * 8 + i;
        if (m >= M) continue;
#pragma unroll
        for (int j = 0; j < 8; j++)
            C[(size_t)m * N + n0 + tx * 8 + j] = acc[i][j] + bias[n0 + tx * 8 + j];
    }
}

__global__ void bf16_to_f32(const __hip_bfloat16* __restrict__ in,
                            float* __restrict__ out, int n)
{
    int i = blockIdx.x * 256 + threadIdx.x;
    if (i < n) out[i] = __bfloat162float(in[i]);
}

// ---------------------------------------------------------------------------
// ctx0 = mean over s of val[b][s][k] -> ctx b-major [32][128]
// ---------------------------------------------------------------------------
__global__ void ctx0_kernel(const float* __restrict__ val, float* __restrict__ ctxb)
{
    int gid = blockIdx.x * 256 + threadIdx.x;
    if (gid >= 4096) return;
    int k = gid >> 5, b = gid & 31;
    float s = 0.f;
    for (int t = 0; t < 208; t++) s += val[((size_t)b * 208 + t) * 128 + k];
    ctxb[b * 128 + k] = s * (1.0f / 208.0f);
}

// ---------------------------------------------------------------------------
// Fused persistent decoder (R7 + R17 early-FCT + R18 release-FCT).
//   blk [0,64):  cell1 — h = blk*8 + tid>>5 in [0,512), b = tid&31
//   blk [64,80): cell2 — h = (blk-64)*8 + tid>>5 in [0,128)
//   blk [80,112): attend — b = blk-80
// Flags (monotonic, value t+1 = "step-t output ready"):
//   FH1[64] by cell1, FH2[16] by cell2, FCT[32] by attend.
// ---------------------------------------------------------------------------
DEV void dec_poll(unsigned* flags, int n, int tid, unsigned tv)
{
    if (tid < n) {
        int guard = 0;
        while (__hip_atomic_load(&flags[tid * FLAG_STRIDE], __ATOMIC_RELAXED,
                                 __HIP_MEMORY_SCOPE_AGENT) < tv) {
            __builtin_amdgcn_s_sleep(1);
            if (++guard > (1 << 15)) break;  // anti-hang
        }
    }
    __syncthreads();
}

DEV void stage64k(const float* gsrc, float* dst, int tid)  // 16384 floats
{
    const unsigned long long* s64 = (const unsigned long long*)gsrc;
#pragma unroll
    for (int half = 0; half < 2; half++) {
        unsigned long long v[16];
#pragma unroll
        for (int j = 0; j < 16; j++)
            v[j] = ld_coh64(&s64[tid + (half * 16 + j) * 256]);
#pragma unroll
        for (int j = 0; j < 16; j++)
            *(unsigned long long*)&dst[2 * (tid + (half * 16 + j) * 256)] = v[j];
    }
}

DEV void stage16k(const float* gsrc, float* dst, int tid)  // 4096 floats
{
    const unsigned long long* s64 = (const unsigned long long*)gsrc;
    unsigned long long v[8];
#pragma unroll
    for (int j = 0; j < 8; j++) v[j] = ld_coh64(&s64[tid + j * 256]);
#pragma unroll
    for (int j = 0; j < 8; j++)
        *(unsigned long long*)&dst[2 * (tid + j * 256)] = v[j];
}

__global__ __launch_bounds__(256, 1) void dec_fused(
    const float* __restrict__ TBL,    // [30][2048] = emb@d1_Wih[:, :256]^T + d1_b
    const int* __restrict__ y,        // [32][200]
    const float* __restrict__ d1_Wih, // [2048][384]
    const float* __restrict__ d1_Whh, // [2048][512]
    const float* __restrict__ d2_Wih, // [512][512]
    const float* __restrict__ d2_Whh, // [512][128]
    const float* __restrict__ d2_b,   // [512]
    const float* __restrict__ KEY, const float* __restrict__ VAL,  // [32][208][128]
    const float* __restrict__ emb,    // [30][256]
    const float* __restrict__ b_out,  // [30]
    float* __restrict__ H1,           // [2][512][32]
    float* __restrict__ H2,           // [2][128][32]
    float* __restrict__ CTX,          // [2][32][128] (b-major)
    float* __restrict__ preds,        // [32][200][30]
    float* __restrict__ attn0,        // [200][208]
    unsigned* __restrict__ FLG)
{
    __shared__ __align__(16) float smem[36864];  // 144 KB
    float* wA = smem;            // 16384 floats: big weight (64KB)
    float* wB = smem + 16384;    // 4096 floats: small weight (16KB)
    float* STG = smem + 20480;   // 16384 floats: staging / attend scratch

    const int tid = threadIdx.x;
    const int blk = blockIdx.x;
    unsigned* FH1 = FLG;
    unsigned* FH2 = FLG + 64 * FLAG_STRIDE;
    unsigned* FCT = FLG + 80 * FLAG_STRIDE;

    if (blk < 64) {
        // ------------------------------- cell1 -------------------------------
        const int wg = blk;
        for (int i = tid; i < 32 * 128; i += 256) {           // Whh 32x512
            int rr = i >> 7, c4 = (i & 127) * 4;
            int row = (rr >> 3) * 512 + wg * 8 + (rr & 7);
            *(float4*)&wA[rr * 512 + c4] = *(const float4*)&d1_Whh[(size_t)row * 512 + c4];
        }
        for (int i = tid; i < 32 * 32; i += 256) {            // Wih ctx 32x128
            int rr = i >> 5, c4 = (i & 31) * 4;
            int row = (rr >> 3) * 512 + wg * 8 + (rr & 7);
            *(float4*)&wB[rr * 128 + c4] = *(const float4*)&d1_Wih[(size_t)row * 384 + 256 + c4];
        }
        __syncthreads();

        const int hl = tid >> 5, b = tid & 31;
        const int h = wg * 8 + hl;
        float c1 = 0.f;
        for (int t = 0; t < 200; t++) {
            dec_poll(FH1, 64, tid, (unsigned)t);          // h1(t-1) ready
            stage64k(H1 + (t & 1) * 16384, STG, tid);     // [512][32] linear
            __syncthreads();
            int tok = (t == 0) ? 0 : y[b * 200 + t - 1];
            float acc[4];
#pragma unroll
            for (int g = 0; g < 4; g++) acc[g] = TBL[(size_t)tok * 2048 + g * 512 + h];
#pragma unroll 2
            for (int q = 0; q < 128; q++) {
                float hv0 = STG[(q * 4 + 0) * 32 + b];
                float hv1 = STG[(q * 4 + 1) * 32 + b];
                float hv2 = STG[(q * 4 + 2) * 32 + b];
                float hv3 = STG[(q * 4 + 3) * 32 + b];
#pragma unroll
                for (int g = 0; g < 4; g++) {
                    float4 w4 = *(const float4*)&wA[(g * 8 + hl) * 512 + q * 4];
                    acc[g] = fmaf(hv0, w4.x, fmaf(hv1, w4.y, fmaf(hv2, w4.z, fmaf(hv3, w4.w, acc[g]))));
                }
            }
            dec_poll(FCT, 32, tid, (unsigned)t);  // ctx(t-1) ready; sync also
                                                  // guards STG reuse below
            {   // stage ctx(t-1) [32][128] -> padded LDS [32][130]
                const unsigned long long* s64 =
                    (const unsigned long long*)(CTX + (t & 1) * 4096);
                unsigned long long v[8];
#pragma unroll
                for (int j = 0; j < 8; j++) v[j] = ld_coh64(&s64[tid + j * 256]);
#pragma unroll
                for (int j = 0; j < 8; j++) {
                    int e = 2 * (tid + j * 256);
                    int bb = e >> 7, k = e & 127;
                    STG[bb * 130 + k] = __uint_as_float((unsigned)v[j]);
                    STG[bb * 130 + k + 1] = __uint_as_float((unsigned)(v[j] >> 32));
                }
            }
            __syncthreads();
#pragma unroll 2
            for (int q = 0; q < 32; q++) {
                float hv0 = STG[b * 130 + q * 4 + 0];
                float hv1 = STG[b * 130 + q * 4 + 1];
                float hv2 = STG[b * 130 + q * 4 + 2];
                float hv3 = STG[b * 130 + q * 4 + 3];
#pragma unroll
                for (int g = 0; g < 4; g++) {
                    float4 w4 = *(const float4*)&wB[(g * 8 + hl) * 128 + q * 4];
                    acc[g] = fmaf(hv0, w4.x, fmaf(hv1, w4.y, fmaf(hv2, w4.z, fmaf(hv3, w4.w, acc[g]))));
                }
            }
            float ci = sigmf(acc[0]), cf = sigmf(acc[1]);
            float cg = tanh_(acc[2]), co = sigmf(acc[3]);
            c1 = cf * c1 + ci * cg;
            float hval = co * tanh_(c1);
            st_coh(&H1[((t + 1) & 1) * 16384 + h * 32 + b], hval);
            __syncthreads();  // drain: H1 stores span all 4 waves
            if (tid == 0)
                __hip_atomic_store(&FH1[wg * FLAG_STRIDE], (unsigned)(t + 1),
                                   __ATOMIC_RELAXED, __HIP_MEMORY_SCOPE_AGENT);
        }
    } else if (blk < 80) {
        // ------------------------------- cell2 -------------------------------
        const int wg = blk - 64;
        for (int i = tid; i < 32 * 128; i += 256) {           // Wih 32x512
            int rr = i >> 7, c4 = (i & 127) * 4;
            int row = (rr >> 3) * 128 + wg * 8 + (rr & 7);
            *(float4*)&wA[rr * 512 + c4] = *(const float4*)&d2_Wih[(size_t)row * 512 + c4];
        }
        for (int i = tid; i < 32 * 32; i += 256) {            // Whh 32x128
            int rr = i >> 5, c4 = (i & 31) * 4;
            int row = (rr >> 3) * 128 + wg * 8 + (rr & 7);
            *(float4*)&wB[rr * 128 + c4] = *(const float4*)&d2_Whh[(size_t)row * 128 + c4];
        }
        __syncthreads();

        const int hl = tid >> 5, b = tid & 31;
        const int h = wg * 8 + hl;
        float bias_r[4];
#pragma unroll
        for (int g = 0; g < 4; g++) bias_r[g] = d2_b[g * 128 + h];
        float c2 = 0.f;
        for (int t = 0; t < 200; t++) {
            dec_poll(FH2, 16, tid, (unsigned)t);          // h2(t-1) ready
            stage16k(H2 + (t & 1) * 4096, STG, tid);      // [128][32] linear
            __syncthreads();
            float acc[4];
#pragma unroll
            for (int g = 0; g < 4; g++) acc[g] = bias_r[g];
#pragma unroll 2
            for (int q = 0; q < 32; q++) {
                float hv0 = STG[(q * 4 + 0) * 32 + b];
                float hv1 = STG[(q * 4 + 1) * 32 + b];
                float hv2 = STG[(q * 4 + 2) * 32 + b];
                float hv3 = STG[(q * 4 + 3) * 32 + b];
#pragma unroll
                for (int g = 0; g < 4; g++) {
                    float4 w4 = *(const float4*)&wB[(g * 8 + hl) * 128 + q * 4];
                    acc[g] = fmaf(hv0, w4.x, fmaf(hv1, w4.y, fmaf(hv2, w4.z, fmaf(hv3, w4.w, acc[g]))));
                }
            }
            dec_poll(FH1, 64, tid, (unsigned)(t + 1));    // h1(t) ready; sync
                                                          // guards STG reuse
            stage64k(H1 + ((t + 1) & 1) * 16384, STG, tid);
            __syncthreads();
#pragma unroll 2
            for (int q = 0; q < 128; q++) {
                float hv0 = STG[(q * 4 + 0) * 32 + b];
                float hv1 = STG[(q * 4 + 1) * 32 + b];
                float hv2 = STG[(q * 4 + 2) * 32 + b];
                float hv3 = STG[(q * 4 + 3) * 32 + b];
#pragma unroll
                for (int g = 0; g < 4; g++) {
                    float4 w4 = *(const float4*)&wA[(g * 8 + hl) * 512 + q * 4];
                    acc[g] = fmaf(hv0, w4.x, fmaf(hv1, w4.y, fmaf(hv2, w4.z, fmaf(hv3, w4.w, acc[g]))));
                }
            }
            float ci = sigmf(acc[0]), cf = sigmf(acc[1]);
            float cg = tanh_(acc[2]), co = sigmf(acc[3]);
            c2 = cf * c2 + ci * cg;
            float hval = co * tanh_(c2);
            st_coh(&H2[((t + 1) & 1) * 4096 + h * 32 + b], hval);
            __syncthreads();  // drain: H2 stores span all 4 waves
            if (tid == 0)
                __hip_atomic_store(&FH2[wg * FLAG_STRIDE], (unsigned)(t + 1),
                                   __ATOMIC_RELAXED, __HIP_MEMORY_SCOPE_AGENT);
        }
    } else {
        // ------------------------------- attend ------------------------------
        const int b = blk - 80;
        const int lane = tid & 63, wv = tid >> 6;
        float* qv    = STG;         // [128]
        float* ctx_s = STG + 128;   // [128]
        float* av    = STG + 256;   // [208]
        float* redA  = STG + 512;   // [4] max partials
        float* redB  = STG + 520;   // [4] sum partials
        float* red2  = STG + 640;   // [128] ctx half-sums

        for (int t = 0; t < 200; t++) {
            dec_poll(FH2, 16, tid, (unsigned)(t + 1));    // h2(t) ready
            const float* h2b = H2 + ((t + 1) & 1) * 4096;
            if (tid < 128) qv[tid] = ld_coh32(&h2b[tid * 32 + b]);
            __syncthreads();

            float e = -INFINITY;
            if (tid < 208) {
                float s = 0.f;
                const float* kr = KEY + ((size_t)b * 208 + tid) * 128;
#pragma unroll
                for (int qd = 0; qd < 32; qd++) {
                    float4 k4 = *(const float4*)&kr[qd * 4];
                    float4 q4 = *(const float4*)&qv[qd * 4];
                    s = fmaf(k4.x, q4.x, fmaf(k4.y, q4.y, fmaf(k4.z, q4.z, fmaf(k4.w, q4.w, s))));
                }
                e = s * 0.08838834764831845f;  // 1/sqrt(128)
            }
            // wave-level max, then 4-wave combine
            float m = e;
#pragma unroll
            for (int off = 32; off >= 1; off >>= 1)
                m = fmaxf(m, __shfl_xor(m, off, 64));
            if (lane == 0) redA[wv] = m;
            __syncthreads();
            m = fmaxf(fmaxf(redA[0], redA[1]), fmaxf(redA[2], redA[3]));
            float ex = (tid < 208) ? __expf(e - m) : 0.f;
            float sm = ex;
#pragma unroll
            for (int off = 32; off >= 1; off >>= 1)
                sm += __shfl_xor(sm, off, 64);
            if (lane == 0) redB[wv] = sm;
            __syncthreads();
            float inv = 1.0f / (redB[0] + redB[1] + redB[2] + redB[3]);
            if (tid < 208) av[tid] = ex * inv;
            if (b == 0 && tid < 208) attn0[t * 208 + tid] = ex * inv;
            __syncthreads();

            // ctx[k] = sum_s av[s] * val[b][s][k], split s into 2 halves
            {
                int k = tid & 127, sh = tid >> 7;
                const float* vb = VAL + (size_t)b * 208 * 128 + k;
                int sbase = sh * 104;
                float s0 = 0.f, s1 = 0.f;
#pragma unroll 4
                for (int ss = 0; ss < 104; ss += 2) {
                    s0 = fmaf(av[sbase + ss],     vb[(size_t)(sbase + ss) * 128], s0);
                    s1 = fmaf(av[sbase + ss + 1], vb[(size_t)(sbase + ss + 1) * 128], s1);
                }
                s0 += s1;
                if (sh == 1) red2[k] = s0;
                __syncthreads();
                if (sh == 0) ctx_s[k] = s0 + red2[k];
            }
            __syncthreads();

            if (tid < 64) {  // wave 0: coherent b-major ctx store (512B)
                unsigned long long u =
                    ((unsigned long long)__float_as_uint(ctx_s[2 * tid + 1]) << 32) |
                    __float_as_uint(ctx_s[2 * tid]);
                st_coh64((unsigned long long*)&CTX[((t + 1) & 1) * 4096 + b * 128 + 2 * tid], u);
            }
            // RELEASE publish by tid 0 (wave 0): drains wave 0's CTX stores;
            // no barrier. logits/attn0 are not consumed by other WGs.
            if (tid == 0)
                pub_rel(&FCT[b * FLAG_STRIDE], (unsigned)(t + 1));
            if (tid < 30) {  // logits (tied weights) - off the critical chain
                const float* er = emb + tid * 256;
                float s = b_out[tid];
#pragma unroll 4
                for (int kk = 0; kk < 32; kk++) {
                    float4 e4 = *(const float4*)&er[kk * 4];
                    float4 q4 = *(const float4*)&qv[kk * 4];
                    s = fmaf(e4.x, q4.x, fmaf(e4.y, q4.y, fmaf(e4.z, q4.z, fmaf(e4.w, q4.w, s))));
                }
#pragma unroll 4
                for (int kk = 0; kk < 32; kk++) {
                    float4 e4 = *(const float4*)&er[128 + kk * 4];
                    float4 c4 = *(const float4*)&ctx_s[kk * 4];
                    s = fmaf(e4.x, c4.x, fmaf(e4.y, c4.y, fmaf(e4.z, c4.z, fmaf(e4.w, c4.w, s))));
                }
                preds[((size_t)b * 200 + t) * 30 + tid] = s;
            }
            // next-step qv/ctx_s overwrites are ordered by dec_poll's
            // internal __syncthreads (all threads, incl. logits stragglers).
        }
    }
}

// ---------------------------------------------------------------------------
template <typename ST>
static void run_encoder(const float* x,
                        const float* e_fw_Wih, const float* e_fw_Whh, const float* e_fw_b,
                        const float* e_bw_Wih, const float* e_bw_Whh, const float* e_bw_b,
                        const float* p_fw_Wih, const float* p_fw_Whh, const float* p_fw_b,
                        const float* p_bw_Wih, const float* p_bw_Whh, const float* p_bw_b,
                        ST* A, ST* B, float* HB, unsigned* FLG, float* WT5,
                        hipStream_t stream)
{
    // l0 (split-4, register-resident weights): transpose, zero, 256 WGs.
    hipLaunchKernelGGL(wt5_prep, dim3(2816), dim3(256), 0, stream,
                       e_fw_Whh, e_bw_Whh, e_fw_Wih, e_bw_Wih, WT5);
    hipMemsetAsync(HB, 0, 32768 * 4, stream);
    hipMemsetAsync(FLG, 0, 2 * 128 * FLAG_STRIDE * 4, stream);
    hipLaunchKernelGGL((lstm_l0_s4<ST>), dim3(256), dim3(256), 0, stream,
                       x, WT5, e_fw_b, e_bw_b, A, HB, FLG);

    int Ts[3] = {832, 416, 208};
    const ST* ins[3] = {A, B, A};
    ST* outs[3] = {B, A, B};
    for (int L = 0; L < 3; L++) {
        hipMemsetAsync(HB, 0, 32768 * 4, stream);
        hipMemsetAsync(FLG, 0, 2 * 128 * FLAG_STRIDE * 4, stream);
        // pyr: static LDS ~102KB -> 1 WG/CU naturally
        hipLaunchKernelGGL((lstm_pyr<ST>), dim3(256), dim3(256), 0, stream,
                           ins[L],
                           p_fw_Whh + (size_t)L * 1024 * 256, p_bw_Whh + (size_t)L * 1024 * 256,
                           p_fw_Wih + (size_t)L * 1024 * 1024, p_bw_Wih + (size_t)L * 1024 * 1024,
                           p_fw_b + L * 1024, p_bw_b + L * 1024,
                           outs[L], HB, FLG, Ts[L]);
    }
}

extern "C" void kernel_launch(void* const* d_in, const int* in_sizes, int n_in,
                              void* d_out, int out_size, void* d_ws, size_t ws_size,
                              hipStream_t stream)
{
    const float* x        = (const float*)d_in[0];
    // d_in[1] = x_len: constant 1664 -> enc_len = 208 = S (mask is a no-op)
    const int*   y        = (const int*)d_in[2];
    const float* e_fw_Wih = (const float*)d_in[3];
    const float* e_fw_Whh = (const float*)d_in[4];
    const float* e_fw_b   = (const float*)d_in[5];
    const float* e_bw_Wih = (const float*)d_in[6];
    const float* e_bw_Whh = (const float*)d_in[7];
    const float* e_bw_b   = (const float*)d_in[8];
    const float* p_fw_Wih = (const float*)d_in[9];
    const float* p_fw_Whh = (const float*)d_in[10];
    const float* p_fw_b   = (const float*)d_in[11];
    const float* p_bw_Wih = (const float*)d_in[12];
    const float* p_bw_Whh = (const float*)d_in[13];
    const float* p_bw_b   = (const float*)d_in[14];
    const float* Wk       = (const float*)d_in[15];
    const float* bk       = (const float*)d_in[16];
    const float* Wv       = (const float*)d_in[17];
    const float* bv       = (const float*)d_in[18];
    const float* emb      = (const float*)d_in[19];
    const float* d1_Wih   = (const float*)d_in[20];
    const float* d1_Whh   = (const float*)d_in[21];
    const float* d1_b     = (const float*)d_in[22];
    const float* d2_Wih   = (const float*)d_in[23];
    const float* d2_Whh   = (const float*)d_in[24];
    const float* d2_b     = (const float*)d_in[25];
    const float* b_out    = (const float*)d_in[26];

    char* base = (char*)d_ws;
    size_t off = 0;
    auto alloc = [&](size_t bytes) -> void* {
        void* p = base + off;
        off = (off + bytes + 255) & ~(size_t)255;
        return p;
    };

    // misc (both plans)
    float*    KEY = (float*)alloc(851968ull * 4);
    float*    VAL = (float*)alloc(851968ull * 4);
    float*    TBL = (float*)alloc(61440ull * 4);
    float*    HB  = (float*)alloc(32768ull * 4);
    unsigned* FLG = (unsigned*)alloc(2 * 128 * FLAG_STRIDE * 4);
    float*    H1  = (float*)alloc(32768ull * 4);
    float*    H2  = (float*)alloc(8192ull * 4);
    float*    CTX = (float*)alloc(8192ull * 4);
    float*    WT5 = (float*)alloc(720896ull * 4);  // l0 split-4 k-major weights

    const size_t A_elems = 32ull * 1664 * 512;  // 27,262,976
    const size_t B_elems = 32ull * 832 * 512;   // 13,631,488
    const size_t L3_elems = 32ull * 208 * 512;  //  3,407,872

    size_t misc_end = off;
    size_t need_f32  = misc_end + (A_elems + B_elems) * 4 + 2048;
    size_t need_bf16 = misc_end + L3_elems * 4 + (A_elems + B_elems) * 2 + 2048;

    const float* enc_out;  // fp32 [6656][512] view of final encoder output
    if (ws_size >= need_f32) {
        float* A = (float*)alloc(A_elems * 4);
        float* B = (float*)alloc(B_elems * 4);
        run_encoder<float>(x, e_fw_Wih, e_fw_Whh, e_fw_b, e_bw_Wih, e_bw_Whh, e_bw_b,
                           p_fw_Wih, p_fw_Whh, p_fw_b, p_bw_Wih, p_bw_Whh, p_bw_b,
                           A, B, HB, FLG, WT5, stream);
        enc_out = B;
    } else if (ws_size >= need_bf16) {
        float* CONV = (float*)alloc(L3_elems * 4);
        __hip_bfloat16* A = (__hip_bfloat16*)alloc(A_elems * 2);
        __hip_bfloat16* B = (__hip_bfloat16*)alloc(B_elems * 2);
        run_encoder<__hip_bfloat16>(x, e_fw_Wih, e_fw_Whh, e_fw_b, e_bw_Wih, e_bw_Whh, e_bw_b,
                                    p_fw_Wih, p_fw_Whh, p_fw_b, p_bw_Wih, p_bw_Whh, p_bw_b,
                                    A, B, HB, FLG, WT5, stream);
        hipLaunchKernelGGL(bf16_to_f32, dim3((unsigned)(L3_elems / 256)), dim3(256), 0, stream,
                           B, CONV, (int)L3_elems);
        enc_out = CONV;
    } else {
        return;  // workspace too small for any plan
    }

    // ---- key / val projections + decoder precompute ----
    hipLaunchKernelGGL(gemm_bt, dim3(52, 1), dim3(256), 0, stream,
                       enc_out, Wk, bk, KEY, 6656, 128, 512, 512);
    hipLaunchKernelGGL(gemm_bt, dim3(52, 1), dim3(256), 0, stream,
                       enc_out, Wv, bv, VAL, 6656, 128, 512, 512);
    hipLaunchKernelGGL(gemm_bt, dim3(1, 16), dim3(256), 0, stream,
                       emb, d1_Wih, d1_b, TBL, 30, 2048, 256, 384);
    hipLaunchKernelGGL(ctx0_kernel, dim3(16), dim3(256), 0, stream, VAL, CTX);
    hipMemsetAsync(H1, 0, 32768 * 4, stream);
    hipMemsetAsync(H2, 0, 8192 * 4, stream);
    hipMemsetAsync(FLG, 0, 2 * 128 * FLAG_STRIDE * 4, stream);

    float* preds = (float*)d_out;
    float* attn0 = (float*)d_out + 192000;

    // ---- fused persistent decoder: 1 launch, 200 steps ----
    hipLaunchKernelGGL(dec_fused, dim3(112), dim3(256), 0, stream,
                       TBL, y, d1_Wih, d1_Whh, d2_Wih, d2_Whh, d2_b,
                       KEY, VAL, emb, b_out, H1, H2, CTX, preds, attn0, FLG);
}

// Round 13
// 27328.992 us; speedup vs baseline: 1.4025x; 1.4025x over previous
//
#include <hip/hip_runtime.h>
#include <hip/hip_bf16.h>
#include <math.h>
#include <stdint.h>

// Seq2Seq LAS model. B=32, T=1664, F_IN=80, H_ENC=256, KV=128, D_DEC=512,
// EMB=256, VOCAB=30, L=200.
// R19 = R17 exact revert (best verified: 27.40 ms).
//  - R18's release-publish regressed 27.4->38.3ms: agent-scope RELEASE on
//    gfx950 emits an L2-writeback sequence before the flag store (cache
//    maintenance, not just vmcnt drain) - far costlier than the barrier it
//    replaced. Relaxed atomics + __syncthreads is the cheap path.
//  - pyr: R8-exact (3 overlap attempts all failed: 2 spills, 1 latency
//    exposure). l0: R13 split-4 + register-resident weights. decoder: R7
//    fused + R17 early-FCT publish. GEMMs unchanged.

#define DEV __device__ __forceinline__

#define FLAG_STRIDE 16  // dwords; one flag per 64B line

DEV float sigmf(float x) { return 1.0f / (1.0f + __expf(-x)); }
DEV float tanh_(float x) { return 1.0f - 2.0f / (__expf(2.0f * x) + 1.0f); }

struct __align__(8) bf4 { __hip_bfloat16 a, b, c, d; };

DEV float4 ld4g(const float* p) { return *(const float4*)p; }
DEV float4 ld4g(const __hip_bfloat16* p) {
    bf4 v = *(const bf4*)p;
    return make_float4(__bfloat162float(v.a), __bfloat162float(v.b),
                       __bfloat162float(v.c), __bfloat162float(v.d));
}
DEV void st1g(float* p, float v) { *p = v; }
DEV void st1g(__hip_bfloat16* p, float v) { *p = __float2bfloat16(v); }

DEV void st_coh(float* p, float v) {
    __hip_atomic_store(p, v, __ATOMIC_RELAXED, __HIP_MEMORY_SCOPE_AGENT);
}
DEV unsigned long long ld_coh64(const unsigned long long* p) {
    return __hip_atomic_load(p, __ATOMIC_RELAXED, __HIP_MEMORY_SCOPE_AGENT);
}
DEV float ld_coh32(const float* p) {
    return __hip_atomic_load(p, __ATOMIC_RELAXED, __HIP_MEMORY_SCOPE_AGENT);
}
DEV void st_coh64(unsigned long long* p, unsigned long long v) {
    __hip_atomic_store(p, v, __ATOMIC_RELAXED, __HIP_MEMORY_SCOPE_AGENT);
}

// ---------------------------------------------------------------------------
// step barrier among 128 WGs of one direction. Flags strided 64B apart.
// __syncthreads drains vmcnt (coherent h-stores visible) before flag store.
// ---------------------------------------------------------------------------
DEV void step_barrier(unsigned* myflags, int w, int tid, unsigned tv)
{
    __syncthreads();
    if (tid == 0)
        __hip_atomic_store(&myflags[w * FLAG_STRIDE], tv, __ATOMIC_RELAXED,
                           __HIP_MEMORY_SCOPE_AGENT);
    if (tid < 128) {
        int guard = 0;
        while (__hip_atomic_load(&myflags[tid * FLAG_STRIDE], __ATOMIC_RELAXED,
                                 __HIP_MEMORY_SCOPE_AGENT) < tv) {
            __builtin_amdgcn_s_sleep(1);
            if (++guard > (1 << 15)) break;  // anti-hang: fail loud, not forever
        }
    }
    __syncthreads();
}

// ---------------------------------------------------------------------------
// Weight transpose for split-4 l0: WT5[dir][g][kc][tid][j] with
// row(tid) = (tid>>6)*256 + g*64 + (tid&63), k = kc*4+j:
//   k<256 -> Whh[row][k]; 256<=k<336 -> Wih[row][k-256]; else 0 (pad).
// Total 2*4*88*1024 = 720896 floats.
// ---------------------------------------------------------------------------
__global__ void wt5_prep(const float* __restrict__ whh_f, const float* __restrict__ whh_b,
                         const float* __restrict__ wih_f, const float* __restrict__ wih_b,
                         float* __restrict__ WT5)
{
    int idx = blockIdx.x * 256 + threadIdx.x;
    if (idx >= 720896) return;
    int j = idx & 3, tid = (idx >> 2) & 255, kc = (idx >> 10) % 88, dg = idx / 90112;
    int dir = dg >> 2, g = dg & 3;
    int row = ((tid >> 6) << 8) + g * 64 + (tid & 63);
    int k = kc * 4 + j;
    const float* Whh = dir ? whh_b : whh_f;
    const float* Wih = dir ? wih_b : wih_f;
    float v = 0.f;
    if (k < 256) v = Whh[row * 256 + k];
    else if (k < 336) v = Wih[row * 80 + (k - 256)];
    WT5[idx] = v;
}

// ---------------------------------------------------------------------------
// Encoder layer 0, split-4 + register-resident weights (R13). grid 256:
// g = blk>>6, grp = blk&63, dir = grp>>5, b = grp&31. 256 threads: thread =
// gate q=tid>>6 of unit u = g*64+(tid&63). Weights (84 float4/thread) live
// in VGPRs across all 1664 steps. Per step: poll 4 group flags -> 1KB h
// reload -> K=336 register dot -> gates -> 64-unit h slice publish.
// HBUF layout: [grp][par][256] floats. Flags: [grp*4+g].
// ---------------------------------------------------------------------------
template <typename ST>
__global__ __launch_bounds__(256, 1) void lstm_l0_s4(
    const float* __restrict__ x,        // [32][1664][80]
    const float* __restrict__ WT5,      // [2][4][88][256][4]
    const float* __restrict__ bias_f, const float* __restrict__ bias_b,
    ST* __restrict__ out,               // [32][1664][512]
    float* __restrict__ hbuf, unsigned* __restrict__ flags)
{
    const int T = 1664;
    __shared__ __align__(16) float hx[336];  // 0..255 h (k-major), 256..335 x_t
    __shared__ float gs[256];

    const int tid = threadIdx.x;
    const int g = blockIdx.x >> 6;
    const int grp = blockIdx.x & 63;
    const int dir = grp >> 5;
    const int b = grp & 31;

    const float* wp = WT5 + (size_t)(dir * 4 + g) * 90112 + tid * 4;
    const int row = ((tid >> 6) << 8) + g * 64 + (tid & 63);
    const float bias_r = (dir ? bias_b : bias_f)[row];
    float c_reg = 0.f;  // valid for tid<64: unit g*64+tid

    unsigned* gflags = flags + grp * 4 * FLAG_STRIDE;
    float* hb = hbuf + grp * 512;  // [2][256]

    // ---- register-resident weights: 84 float4 = 336 VGPRs (1 wave/SIMD) ----
    float4 wreg[84];
#pragma unroll
    for (int kc = 0; kc < 84; kc++)
        wreg[kc] = *(const float4*)(wp + (size_t)kc * 1024);

    // x prefetch for t=0
    float4 xv = make_float4(0.f, 0.f, 0.f, 0.f);
    if (tid < 20) {
        int t0 = dir ? (T - 1) : 0;
        xv = *(const float4*)&x[((size_t)b * T + t0) * 80 + tid * 4];
    }

    for (int t = 0; t < T; t++) {
        const int par = t & 1;
        const int t_act = dir ? (T - 1 - t) : t;

        if (tid < 20) *(float4*)&hx[256 + tid * 4] = xv;
        if (tid < 20 && t + 1 < T) {  // prefetch next step's x
            int tn = dir ? (T - 2 - t) : (t + 1);
            xv = *(const float4*)&x[((size_t)b * T + tn) * 80 + tid * 4];
        }

        // ---- wait for all 4 group slices of h(t-1) ----
        if (tid < 4) {
            int guard = 0;
            while (__hip_atomic_load(&gflags[tid * FLAG_STRIDE], __ATOMIC_RELAXED,
                                     __HIP_MEMORY_SCOPE_AGENT) < (unsigned)t) {
                __builtin_amdgcn_s_sleep(1);
                if (++guard > (1 << 16)) break;  // anti-hang
            }
        }
        __syncthreads();  // S0: flags seen by whole WG

        // ---- coherent h reload (1KB, k-major: no transpose) ----
        if (tid < 128) {
            unsigned long long v =
                ld_coh64((const unsigned long long*)(hb + par * 256) + tid);
            hx[2 * tid] = __uint_as_float((unsigned)v);
            hx[2 * tid + 1] = __uint_as_float((unsigned)(v >> 32));
        }
        __syncthreads();  // S1: h + x visible

        // ---- K=336 dot from register weights; 4 accumulators ----
        float a0 = bias_r, a1 = 0.f, a2 = 0.f, a3 = 0.f;
#pragma unroll
        for (int kc = 0; kc < 84; kc += 4) {
            float4 w0 = wreg[kc + 0], w1 = wreg[kc + 1];
            float4 w2 = wreg[kc + 2], w3 = wreg[kc + 3];
            float4 h0 = *(const float4*)&hx[(kc + 0) * 4];
            float4 h1 = *(const float4*)&hx[(kc + 1) * 4];
            float4 h2 = *(const float4*)&hx[(kc + 2) * 4];
            float4 h3 = *(const float4*)&hx[(kc + 3) * 4];
            a0 = fmaf(w0.x, h0.x, fmaf(w0.y, h0.y, fmaf(w0.z, h0.z, fmaf(w0.w, h0.w, a0))));
            a1 = fmaf(w1.x, h1.x, fmaf(w1.y, h1.y, fmaf(w1.z, h1.z, fmaf(w1.w, h1.w, a1))));
            a2 = fmaf(w2.x, h2.x, fmaf(w2.y, h2.y, fmaf(w2.z, h2.z, fmaf(w2.w, h2.w, a2))));
            a3 = fmaf(w3.x, h3.x, fmaf(w3.y, h3.y, fmaf(w3.z, h3.z, fmaf(w3.w, h3.w, a3))));
        }
        gs[tid] = (a0 + a1) + (a2 + a3);
        __syncthreads();  // S2: gates ready; all dot-reads of hx done

        if (tid < 64) {
            float gi = gs[tid], gf = gs[64 + tid];
            float gg = gs[128 + tid], go = gs[192 + tid];
            float ci = sigmf(gi), cf = sigmf(gf), cg = tanh_(gg), co = sigmf(go);
            c_reg = cf * c_reg + ci * cg;
            float hval = co * tanh_(c_reg);
            // 64 lanes -> 256B contiguous slice of next-parity h buffer
            st_coh(&hb[(par ^ 1) * 256 + g * 64 + tid], hval);
            st1g(&out[((size_t)b * T + t_act) * 512 + dir * 256 + g * 64 + tid], hval);
        }
        __syncthreads();  // S3: drain coherent h-stores before publish
        if (tid == 0)
            __hip_atomic_store(&gflags[g * FLAG_STRIDE], (unsigned)(t + 1),
                               __ATOMIC_RELAXED, __HIP_MEMORY_SCOPE_AGENT);
    }
}

// ---------------------------------------------------------------------------
// Pyramid layer (persistent, R8 exact). K = 1280 = 256 h (resident hsh,
// swizzled) + 4 in-groups of 256 (ping-pong is[2], lane-contiguous staging).
// 5 barriers + step barrier. in-group g: row 2t+(g>>1), cols (g&1)*256..+255.
// ---------------------------------------------------------------------------
template <typename ST>
__global__ __launch_bounds__(256, 1) void lstm_pyr(
    const ST* __restrict__ in,          // [32][2*Tn][512]
    const float* __restrict__ whh_f, const float* __restrict__ whh_b,  // [1024][256]
    const float* __restrict__ wih_f, const float* __restrict__ wih_b,  // [1024][1024]
    const float* __restrict__ bias_f, const float* __restrict__ bias_b,
    ST* __restrict__ out,               // [32][Tn][512]
    float* __restrict__ hbuf, unsigned* __restrict__ flags, int Tn)
{
    const int RS = 260;  // row stride (4-aligned)
    __shared__ __align__(16) float hsh[32 * 260];
    __shared__ __align__(16) float is[2][32 * 260];
    __shared__ float pb[4][32][9];

    const int tid = threadIdx.x;
    const int dir = blockIdx.x >> 7;
    const int w = blockIdx.x & 127;
    const int wave = tid >> 6, lane = tid & 63;
    const int cl = lane & 7;
    const int ksub = lane >> 3;
    const int slot = (wave * 8 + ksub) * 4;
    const int col = (cl >> 1) * 256 + w * 2 + (cl & 1);
    const int Tprev = 2 * Tn;

    const float* Whh = dir ? whh_b : whh_f;
    const float* Wih = dir ? wih_b : wih_f;
    const float* bias = dir ? bias_b : bias_f;

    float4 wreg[10];
#pragma unroll
    for (int c = 0; c < 10; c++) {
        int k = c * 128 + slot;
        wreg[c] = (k < 256)
            ? *(const float4*)&Whh[(size_t)col * 256 + k]
            : *(const float4*)&Wih[(size_t)col * 1024 + (k - 256)];
    }

    const int sb = tid >> 3, q7 = tid & 7;  // in-staging role (lane-contiguous)
    const int qb = tid >> 1, qj = tid & 1;
    float bias_g[4];
#pragma unroll
    for (int g = 0; g < 4; g++) bias_g[g] = bias[g * 256 + w * 2 + (tid & 1)];
    float c_reg = 0.f;

    unsigned* myflags = flags + dir * 128 * FLAG_STRIDE;
    float* hb_base = hbuf + dir * 2 * 8192;

    for (int t = 0; t < Tn; t++) {
        const int par = t & 1;
        const int t_act = dir ? (Tn - 1 - t) : t;
        const unsigned long long* h64 =
            (const unsigned long long*)(hb_base + par * 8192);

        float acc[32];
#pragma unroll
        for (int b = 0; b < 32; b++) acc[b] = 0.f;

        // helper: load in-group g into registers (cols q7*4 + i*32: 8-lane
        // groups read/write contiguous 128B segments -> conflict-free)
        float4 gbuf[8];
        auto load_grp = [&](int g) {
            int r = 2 * t_act + (g >> 1);
            int cb = (g & 1) * 256;
            const ST* src = &in[((size_t)sb * Tprev + r) * 512 + cb + q7 * 4];
#pragma unroll
            for (int i = 0; i < 8; i++) gbuf[i] = ld4g(src + i * 32);
        };
        auto commit_grp = [&](int buf) {
#pragma unroll
            for (int i = 0; i < 8; i++)
                *(float4*)&is[buf][sb * RS + q7 * 4 + i * 32] = gbuf[i];
        };
        auto dot2 = [&](const float* base, int wi) {
#pragma unroll
            for (int cc = 0; cc < 2; cc++) {
                float4 wv = wreg[wi + cc];
                const float* src = base + cc * 128 + slot;
#pragma unroll
                for (int b = 0; b < 32; b++) {
                    float4 hv = *(const float4*)&src[b * RS];
                    acc[b] = fmaf(hv.x, wv.x, fmaf(hv.y, wv.y, fmaf(hv.z, wv.z, fmaf(hv.w, wv.w, acc[b]))));
                }
            }
        };
        auto dot2s = [&]() {  // h chunks from hsh (swizzled rows)
#pragma unroll
            for (int cc = 0; cc < 2; cc++) {
                float4 wv = wreg[cc];
                const int kb = cc * 128 + slot;
#pragma unroll
                for (int b = 0; b < 32; b++) {
                    float4 hv = *(const float4*)&hsh[b * RS + (kb ^ (((b >> 1) & 7) << 2))];
                    acc[b] = fmaf(hv.x, wv.x, fmaf(hv.y, wv.y, fmaf(hv.z, wv.z, fmaf(hv.w, wv.w, acc[b]))));
                }
            }
        };

        // ---- coherent wide h reload + group 0 ----
        unsigned long long hv64[16];
#pragma unroll
        for (int j = 0; j < 16; j++)
            hv64[j] = ld_coh64(&h64[tid + j * 256]);
        load_grp(0);
#pragma unroll
        for (int j = 0; j < 16; j++) {
            int q = tid + j * 256;
            int u = q >> 4, b0 = (q & 15) * 2;
            int uc = u ^ ((q & 7) << 2);
            hsh[b0 * RS + uc] = __uint_as_float((unsigned)hv64[j]);
            hsh[(b0 + 1) * RS + uc] = __uint_as_float((unsigned)(hv64[j] >> 32));
        }
        commit_grp(0);  // -> is[0]
        __syncthreads();  // S1

        load_grp(1);
        dot2s();                      // h chunks c0,c1 (swizzled hsh)
        dot2(&is[0][0], 2);           // c2,c3
        commit_grp(1);  // -> is[1]
        __syncthreads();  // S2

        load_grp(2);
        dot2(&is[1][0], 4);           // c4,c5
        commit_grp(0);  // -> is[0]
        __syncthreads();  // S3

        load_grp(3);
        dot2(&is[0][0], 6);           // c6,c7
        commit_grp(1);  // -> is[1]
        __syncthreads();  // S4

        dot2(&is[1][0], 8);           // c8,c9

#pragma unroll
        for (int b = 0; b < 32; b++) {
            acc[b] += __shfl_xor(acc[b], 8, 64);
            acc[b] += __shfl_xor(acc[b], 16, 64);
            acc[b] += __shfl_xor(acc[b], 32, 64);
        }
#pragma unroll
        for (int i = 0; i < 4; i++)
            pb[wave][ksub * 4 + i][cl] = acc[ksub * 4 + i];
        __syncthreads();  // S5

        if (tid < 64) {
            float ga[4];
#pragma unroll
            for (int gg = 0; gg < 4; gg++) {
                float s = bias_g[gg];
#pragma unroll
                for (int v = 0; v < 4; v++) s += pb[v][qb][gg * 2 + qj];
                ga[gg] = s;
            }
            float ci = sigmf(ga[0]), cf = sigmf(ga[1]);
            float cg = tanh_(ga[2]), co = sigmf(ga[3]);
            c_reg = cf * c_reg + ci * cg;
            float hval = co * tanh_(c_reg);
            st_coh(&hb_base[(par ^ 1) * 8192 + (w * 2 + qj) * 32 + qb], hval);
            st1g(&out[((size_t)qb * Tn + t_act) * 512 + dir * 256 + w * 2 + qj], hval);
        }

        step_barrier(myflags, w, tid, (unsigned)(t + 1));
    }
}

// ---------------------------------------------------------------------------
// C[M][N] = A[M][K] @ W[N][K]^T + bias  (fp32, 128x128 tiles, 8x8/thread)
// ---------------------------------------------------------------------------
__global__ __launch_bounds__(256) void gemm_bt(
    const float* __restrict__ A, const float* __restrict__ W,
    const float* __restrict__ bias, float* __restrict__ C,
    int M, int N, int K, int ldw)
{
    __shared__ __align__(16) float As[16][128];
    __shared__ __align__(16) float Ws[16][128];
    int tid = threadIdx.x;
    int m0 = blockIdx.x * 128, n0 = blockIdx.y * 128;
    int tx = tid & 15, ty = tid >> 4;

    float acc[8][8];
#pragma unroll
    for (int i = 0; i < 8; i++)
#pragma unroll
        for (int j = 0; j < 8; j++) acc[i][j] = 0.f;

    for (int kb = 0; kb < K; kb += 16) {
#pragma unroll
        for (int l = 0; l < 2; l++) {
            int idx = tid + l * 256;
            int row = idx >> 2, kq = (idx & 3) * 4;
            float4 v = make_float4(0.f, 0.f, 0.f, 0.f);
            if (m0 + row < M)
                v = *(const float4*)&A[(size_t)(m0 + row) * K + kb + kq];
            As[kq + 0][row] = v.x; As[kq + 1][row] = v.y;
            As[kq + 2][row] = v.z; As[kq + 3][row] = v.w;
        }
#pragma unroll
        for (int l = 0; l < 2; l++) {
            int idx = tid + l * 256;
            int row = idx >> 2, kq = (idx & 3) * 4;
            float4 v = *(const float4*)&W[(size_t)(n0 + row) * ldw + kb + kq];
            Ws[kq + 0][row] = v.x; Ws[kq + 1][row] = v.y;
            Ws[kq + 2][row] = v.z; Ws[kq + 3][row] = v.w;
        }
        __syncthreads();
#pragma unroll
        for (int k = 0; k < 16; k++) {
            float a[8], b[8];
            *(float4*)&a[0] = *(const float4*)&As[k][ty * 8];
            *(float4*)&a[4] = *(const float4*)&As[k][ty * 8 + 4];
            *(float4*)&b[0] = *(const float4*)&Ws[k][tx * 8];
            *(float4*)&b[4] = *(const float4*)&Ws[k][tx * 8 + 4];
#pragma unroll
            for (int i = 0; i < 8; i++)
#pragma unroll
                for (int j = 0; j < 8; j++)
                    acc[i][j] = fmaf(a[i], b[j], acc[i][j]);
        }
        __syncthreads();
    }
#pragma unroll
    for (int i = 0; i < 8; i++) {
        int m = m0 + ty * 8 + i;
        if (m >= M) continue;
#pragma unroll
        for (int j = 0; j < 8; j++)
            C[(size_t)m * N + n0 + tx * 8 + j] = acc[i][j] + bias[n0 + tx * 8 + j];
    }
}

__global__ void bf16_to_f32(const __hip_bfloat16* __restrict__ in,
                            float* __restrict__ out, int n)
{
    int i = blockIdx.x * 256 + threadIdx.x;
    if (i < n) out[i] = __bfloat162float(in[i]);
}

// ---------------------------------------------------------------------------
// ctx0 = mean over s of val[b][s][k] -> ctx b-major [32][128]
// ---------------------------------------------------------------------------
__global__ void ctx0_kernel(const float* __restrict__ val, float* __restrict__ ctxb)
{
    int gid = blockIdx.x * 256 + threadIdx.x;
    if (gid >= 4096) return;
    int k = gid >> 5, b = gid & 31;
    float s = 0.f;
    for (int t = 0; t < 208; t++) s += val[((size_t)b * 208 + t) * 128 + k];
    ctxb[b * 128 + k] = s * (1.0f / 208.0f);
}

// ---------------------------------------------------------------------------
// Fused persistent decoder (R7 + R17 early-FCT-publish). One launch, 200
// steps.
//   blk [0,64):  cell1 — h = blk*8 + tid>>5 in [0,512), b = tid&31
//   blk [64,80): cell2 — h = (blk-64)*8 + tid>>5 in [0,128)
//   blk [80,112): attend — b = blk-80
// Flags (monotonic, value t+1 = "step-t output ready"):
//   FH1[64] by cell1, FH2[16] by cell2, FCT[32] by attend.
// ---------------------------------------------------------------------------
DEV void dec_poll(unsigned* flags, int n, int tid, unsigned tv)
{
    if (tid < n) {
        int guard = 0;
        while (__hip_atomic_load(&flags[tid * FLAG_STRIDE], __ATOMIC_RELAXED,
                                 __HIP_MEMORY_SCOPE_AGENT) < tv) {
            __builtin_amdgcn_s_sleep(1);
            if (++guard > (1 << 15)) break;  // anti-hang
        }
    }
    __syncthreads();
}

DEV void stage64k(const float* gsrc, float* dst, int tid)  // 16384 floats
{
    const unsigned long long* s64 = (const unsigned long long*)gsrc;
#pragma unroll
    for (int half = 0; half < 2; half++) {
        unsigned long long v[16];
#pragma unroll
        for (int j = 0; j < 16; j++)
            v[j] = ld_coh64(&s64[tid + (half * 16 + j) * 256]);
#pragma unroll
        for (int j = 0; j < 16; j++)
            *(unsigned long long*)&dst[2 * (tid + (half * 16 + j) * 256)] = v[j];
    }
}

DEV void stage16k(const float* gsrc, float* dst, int tid)  // 4096 floats
{
    const unsigned long long* s64 = (const unsigned long long*)gsrc;
    unsigned long long v[8];
#pragma unroll
    for (int j = 0; j < 8; j++) v[j] = ld_coh64(&s64[tid + j * 256]);
#pragma unroll
    for (int j = 0; j < 8; j++)
        *(unsigned long long*)&dst[2 * (tid + j * 256)] = v[j];
}

__global__ __launch_bounds__(256, 1) void dec_fused(
    const float* __restrict__ TBL,    // [30][2048] = emb@d1_Wih[:, :256]^T + d1_b
    const int* __restrict__ y,        // [32][200]
    const float* __restrict__ d1_Wih, // [2048][384]
    const float* __restrict__ d1_Whh, // [2048][512]
    const float* __restrict__ d2_Wih, // [512][512]
    const float* __restrict__ d2_Whh, // [512][128]
    const float* __restrict__ d2_b,   // [512]
    const float* __restrict__ KEY, const float* __restrict__ VAL,  // [32][208][128]
    const float* __restrict__ emb,    // [30][256]
    const float* __restrict__ b_out,  // [30]
    float* __restrict__ H1,           // [2][512][32]
    float* __restrict__ H2,           // [2][128][32]
    float* __restrict__ CTX,          // [2][32][128] (b-major)
    float* __restrict__ preds,        // [32][200][30]
    float* __restrict__ attn0,        // [200][208]
    unsigned* __restrict__ FLG)
{
    __shared__ __align__(16) float smem[36864];  // 144 KB
    float* wA = smem;            // 16384 floats: big weight (64KB)
    float* wB = smem + 16384;    // 4096 floats: small weight (16KB)
    float* STG = smem + 20480;   // 16384 floats: staging / attend scratch

    const int tid = threadIdx.x;
    const int blk = blockIdx.x;
    unsigned* FH1 = FLG;
    unsigned* FH2 = FLG + 64 * FLAG_STRIDE;
    unsigned* FCT = FLG + 80 * FLAG_STRIDE;

    if (blk < 64) {
        // ------------------------------- cell1 -------------------------------
        const int wg = blk;
        for (int i = tid; i < 32 * 128; i += 256) {           // Whh 32x512
            int rr = i >> 7, c4 = (i & 127) * 4;
            int row = (rr >> 3) * 512 + wg * 8 + (rr & 7);
            *(float4*)&wA[rr * 512 + c4] = *(const float4*)&d1_Whh[(size_t)row * 512 + c4];
        }
        for (int i = tid; i < 32 * 32; i += 256) {            // Wih ctx 32x128
            int rr = i >> 5, c4 = (i & 31) * 4;
            int row = (rr >> 3) * 512 + wg * 8 + (rr & 7);
            *(float4*)&wB[rr * 128 + c4] = *(const float4*)&d1_Wih[(size_t)row * 384 + 256 + c4];
        }
        __syncthreads();

        const int hl = tid >> 5, b = tid & 31;
        const int h = wg * 8 + hl;
        float c1 = 0.f;
        for (int t = 0; t < 200; t++) {
            dec_poll(FH1, 64, tid, (unsigned)t);          // h1(t-1) ready
            stage64k(H1 + (t & 1) * 16384, STG, tid);     // [512][32] linear
            __syncthreads();
            int tok = (t == 0) ? 0 : y[b * 200 + t - 1];
            float acc[4];
#pragma unroll
            for (int g = 0; g < 4; g++) acc[g] = TBL[(size_t)tok * 2048 + g * 512 + h];
#pragma unroll 2
            for (int q = 0; q < 128; q++) {
                float hv0 = STG[(q * 4 + 0) * 32 + b];
                float hv1 = STG[(q * 4 + 1) * 32 + b];
                float hv2 = STG[(q * 4 + 2) * 32 + b];
                float hv3 = STG[(q * 4 + 3) * 32 + b];
#pragma unroll
                for (int g = 0; g < 4; g++) {
                    float4 w4 = *(const float4*)&wA[(g * 8 + hl) * 512 + q * 4];
                    acc[g] = fmaf(hv0, w4.x, fmaf(hv1, w4.y, fmaf(hv2, w4.z, fmaf(hv3, w4.w, acc[g]))));
                }
            }
            dec_poll(FCT, 32, tid, (unsigned)t);  // ctx(t-1) ready; sync also
                                                  // guards STG reuse below
            {   // stage ctx(t-1) [32][128] -> padded LDS [32][130]
                const unsigned long long* s64 =
                    (const unsigned long long*)(CTX + (t & 1) * 4096);
                unsigned long long v[8];
#pragma unroll
                for (int j = 0; j < 8; j++) v[j] = ld_coh64(&s64[tid + j * 256]);
#pragma unroll
                for (int j = 0; j < 8; j++) {
                    int e = 2 * (tid + j * 256);
                    int bb = e >> 7, k = e & 127;
                    STG[bb * 130 + k] = __uint_as_float((unsigned)v[j]);
                    STG[bb * 130 + k + 1] = __uint_as_float((unsigned)(v[j] >> 32));
                }
            }
            __syncthreads();
#pragma unroll 2
            for (int q = 0; q < 32; q++) {
                float hv0 = STG[b * 130 + q * 4 + 0];
                float hv1 = STG[b * 130 + q * 4 + 1];
                float hv2 = STG[b * 130 + q * 4 + 2];
                float hv3 = STG[b * 130 + q * 4 + 3];
#pragma unroll
                for (int g = 0; g < 4; g++) {
                    float4 w4 = *(const float4*)&wB[(g * 8 + hl) * 128 + q * 4];
                    acc[g] = fmaf(hv0, w4.x, fmaf(hv1, w4.y, fmaf(hv2, w4.z, fmaf(hv3, w4.w, acc[g]))));
                }
            }
            float ci = sigmf(acc[0]), cf = sigmf(acc[1]);
            float cg = tanh_(acc[2]), co = sigmf(acc[3]);
            c1 = cf * c1 + ci * cg;
            float hval = co * tanh_(c1);
            st_coh(&H1[((t + 1) & 1) * 16384 + h * 32 + b], hval);
            __syncthreads();  // drain coherent stores
            if (tid == 0)
                __hip_atomic_store(&FH1[wg * FLAG_STRIDE], (unsigned)(t + 1),
                                   __ATOMIC_RELAXED, __HIP_MEMORY_SCOPE_AGENT);
        }
    } else if (blk < 80) {
        // ------------------------------- cell2 -------------------------------
        const int wg = blk - 64;
        for (int i = tid; i < 32 * 128; i += 256) {           // Wih 32x512
            int rr = i >> 7, c4 = (i & 127) * 4;
            int row = (rr >> 3) * 128 + wg * 8 + (rr & 7);
            *(float4*)&wA[rr * 512 + c4] = *(const float4*)&d2_Wih[(size_t)row * 512 + c4];
        }
        for (int i = tid; i < 32 * 32; i += 256) {            // Whh 32x128
            int rr = i >> 5, c4 = (i & 31) * 4;
            int row = (rr >> 3) * 128 + wg * 8 + (rr & 7);
            *(float4*)&wB[rr * 128 + c4] = *(const float4*)&d2_Whh[(size_t)row * 128 + c4];
        }
        __syncthreads();

        const int hl = tid >> 5, b = tid & 31;
        const int h = wg * 8 + hl;
        float bias_r[4];
#pragma unroll
        for (int g = 0; g < 4; g++) bias_r[g] = d2_b[g * 128 + h];
        float c2 = 0.f;
        for (int t = 0; t < 200; t++) {
            dec_poll(FH2, 16, tid, (unsigned)t);          // h2(t-1) ready
            stage16k(H2 + (t & 1) * 4096, STG, tid);      // [128][32] linear
            __syncthreads();
            float acc[4];
#pragma unroll
            for (int g = 0; g < 4; g++) acc[g] = bias_r[g];
#pragma unroll 2
            for (int q = 0; q < 32; q++) {
                float hv0 = STG[(q * 4 + 0) * 32 + b];
                float hv1 = STG[(q * 4 + 1) * 32 + b];
                float hv2 = STG[(q * 4 + 2) * 32 + b];
                float hv3 = STG[(q * 4 + 3) * 32 + b];
#pragma unroll
                for (int g = 0; g < 4; g++) {
                    float4 w4 = *(const float4*)&wB[(g * 8 + hl) * 128 + q * 4];
                    acc[g] = fmaf(hv0, w4.x, fmaf(hv1, w4.y, fmaf(hv2, w4.z, fmaf(hv3, w4.w, acc[g]))));
                }
            }
            dec_poll(FH1, 64, tid, (unsigned)(t + 1));    // h1(t) ready; sync
                                                          // guards STG reuse
            stage64k(H1 + ((t + 1) & 1) * 16384, STG, tid);
            __syncthreads();
#pragma unroll 2
            for (int q = 0; q < 128; q++) {
                float hv0 = STG[(q * 4 + 0) * 32 + b];
                float hv1 = STG[(q * 4 + 1) * 32 + b];
                float hv2 = STG[(q * 4 + 2) * 32 + b];
                float hv3 = STG[(q * 4 + 3) * 32 + b];
#pragma unroll
                for (int g = 0; g < 4; g++) {
                    float4 w4 = *(const float4*)&wA[(g * 8 + hl) * 512 + q * 4];
                    acc[g] = fmaf(hv0, w4.x, fmaf(hv1, w4.y, fmaf(hv2, w4.z, fmaf(hv3, w4.w, acc[g]))));
                }
            }
            float ci = sigmf(acc[0]), cf = sigmf(acc[1]);
            float cg = tanh_(acc[2]), co = sigmf(acc[3]);
            c2 = cf * c2 + ci * cg;
            float hval = co * tanh_(c2);
            st_coh(&H2[((t + 1) & 1) * 4096 + h * 32 + b], hval);
            __syncthreads();
            if (tid == 0)
                __hip_atomic_store(&FH2[wg * FLAG_STRIDE], (unsigned)(t + 1),
                                   __ATOMIC_RELAXED, __HIP_MEMORY_SCOPE_AGENT);
        }
    } else {
        // ------------------------------- attend ------------------------------
        const int b = blk - 80;
        const int lane = tid & 63, wv = tid >> 6;
        float* qv    = STG;         // [128]
        float* ctx_s = STG + 128;   // [128]
        float* av    = STG + 256;   // [208]
        float* redA  = STG + 512;   // [4] max partials
        float* redB  = STG + 520;   // [4] sum partials
        float* red2  = STG + 640;   // [128] ctx half-sums

        for (int t = 0; t < 200; t++) {
            dec_poll(FH2, 16, tid, (unsigned)(t + 1));    // h2(t) ready
            const float* h2b = H2 + ((t + 1) & 1) * 4096;
            if (tid < 128) qv[tid] = ld_coh32(&h2b[tid * 32 + b]);
            __syncthreads();

            float e = -INFINITY;
            if (tid < 208) {
                float s = 0.f;
                const float* kr = KEY + ((size_t)b * 208 + tid) * 128;
#pragma unroll
                for (int qd = 0; qd < 32; qd++) {
                    float4 k4 = *(const float4*)&kr[qd * 4];
                    float4 q4 = *(const float4*)&qv[qd * 4];
                    s = fmaf(k4.x, q4.x, fmaf(k4.y, q4.y, fmaf(k4.z, q4.z, fmaf(k4.w, q4.w, s))));
                }
                e = s * 0.08838834764831845f;  // 1/sqrt(128)
            }
            // wave-level max, then 4-wave combine
            float m = e;
#pragma unroll
            for (int off = 32; off >= 1; off >>= 1)
                m = fmaxf(m, __shfl_xor(m, off, 64));
            if (lane == 0) redA[wv] = m;
            __syncthreads();
            m = fmaxf(fmaxf(redA[0], redA[1]), fmaxf(redA[2], redA[3]));
            float ex = (tid < 208) ? __expf(e - m) : 0.f;
            float sm = ex;
#pragma unroll
            for (int off = 32; off >= 1; off >>= 1)
                sm += __shfl_xor(sm, off, 64);
            if (lane == 0) redB[wv] = sm;
            __syncthreads();
            float inv = 1.0f / (redB[0] + redB[1] + redB[2] + redB[3]);
            if (tid < 208) av[tid] = ex * inv;
            if (b == 0 && tid < 208) attn0[t * 208 + tid] = ex * inv;
            __syncthreads();

            // ctx[k] = sum_s av[s] * val[b][s][k], split s into 2 halves
            {
                int k = tid & 127, sh = tid >> 7;
                const float* vb = VAL + (size_t)b * 208 * 128 + k;
                int sbase = sh * 104;
                float s0 = 0.f, s1 = 0.f;
#pragma unroll 4
                for (int ss = 0; ss < 104; ss += 2) {
                    s0 = fmaf(av[sbase + ss],     vb[(size_t)(sbase + ss) * 128], s0);
                    s1 = fmaf(av[sbase + ss + 1], vb[(size_t)(sbase + ss + 1) * 128], s1);
                }
                s0 += s1;
                if (sh == 1) red2[k] = s0;
                __syncthreads();
                if (sh == 0) ctx_s[k] = s0 + red2[k];
            }
            __syncthreads();

            if (tid < 64) {  // coherent b-major ctx store: 512B contiguous
                unsigned long long u =
                    ((unsigned long long)__float_as_uint(ctx_s[2 * tid + 1]) << 32) |
                    __float_as_uint(ctx_s[2 * tid]);
                st_coh64((unsigned long long*)&CTX[((t + 1) & 1) * 4096 + b * 128 + 2 * tid], u);
            }
            __syncthreads();  // drain coherent ctx stores
            if (tid == 0)     // EARLY publish: logits/attn0 are not consumed
                __hip_atomic_store(&FCT[b * FLAG_STRIDE], (unsigned)(t + 1),
                                   __ATOMIC_RELAXED, __HIP_MEMORY_SCOPE_AGENT);
            if (tid < 30) {  // logits (tied weights) - off the critical chain
                const float* er = emb + tid * 256;
                float s = b_out[tid];
#pragma unroll 4
                for (int kk = 0; kk < 32; kk++) {
                    float4 e4 = *(const float4*)&er[kk * 4];
                    float4 q4 = *(const float4*)&qv[kk * 4];
                    s = fmaf(e4.x, q4.x, fmaf(e4.y, q4.y, fmaf(e4.z, q4.z, fmaf(e4.w, q4.w, s))));
                }
#pragma unroll 4
                for (int kk = 0; kk < 32; kk++) {
                    float4 e4 = *(const float4*)&er[128 + kk * 4];
                    float4 c4 = *(const float4*)&ctx_s[kk * 4];
                    s = fmaf(e4.x, c4.x, fmaf(e4.y, c4.y, fmaf(e4.z, c4.z, fmaf(e4.w, c4.w, s))));
                }
                preds[((size_t)b * 200 + t) * 30 + tid] = s;
            }
            // next-step qv/ctx_s overwrites are ordered by dec_poll's
            // internal __syncthreads (all threads, incl. logits stragglers).
        }
    }
}

// ---------------------------------------------------------------------------
template <typename ST>
static void run_encoder(const float* x,
                        const float* e_fw_Wih, const float* e_fw_Whh, const float* e_fw_b,
                        const float* e_bw_Wih, const float* e_bw_Whh, const float* e_bw_b,
                        const float* p_fw_Wih, const float* p_fw_Whh, const float* p_fw_b,
                        const float* p_bw_Wih, const float* p_bw_Whh, const float* p_bw_b,
                        ST* A, ST* B, float* HB, unsigned* FLG, float* WT5,
                        hipStream_t stream)
{
    // l0 (split-4, register-resident weights): transpose, zero, 256 WGs.
    hipLaunchKernelGGL(wt5_prep, dim3(2816), dim3(256), 0, stream,
                       e_fw_Whh, e_bw_Whh, e_fw_Wih, e_bw_Wih, WT5);
    hipMemsetAsync(HB, 0, 32768 * 4, stream);
    hipMemsetAsync(FLG, 0, 2 * 128 * FLAG_STRIDE * 4, stream);
    hipLaunchKernelGGL((lstm_l0_s4<ST>), dim3(256), dim3(256), 0, stream,
                       x, WT5, e_fw_b, e_bw_b, A, HB, FLG);

    int Ts[3] = {832, 416, 208};
    const ST* ins[3] = {A, B, A};
    ST* outs[3] = {B, A, B};
    for (int L = 0; L < 3; L++) {
        hipMemsetAsync(HB, 0, 32768 * 4, stream);
        hipMemsetAsync(FLG, 0, 2 * 128 * FLAG_STRIDE * 4, stream);
        // pyr: static LDS ~102KB -> 1 WG/CU naturally
        hipLaunchKernelGGL((lstm_pyr<ST>), dim3(256), dim3(256), 0, stream,
                           ins[L],
                           p_fw_Whh + (size_t)L * 1024 * 256, p_bw_Whh + (size_t)L * 1024 * 256,
                           p_fw_Wih + (size_t)L * 1024 * 1024, p_bw_Wih + (size_t)L * 1024 * 1024,
                           p_fw_b + L * 1024, p_bw_b + L * 1024,
                           outs[L], HB, FLG, Ts[L]);
    }
}

extern "C" void kernel_launch(void* const* d_in, const int* in_sizes, int n_in,
                              void* d_out, int out_size, void* d_ws, size_t ws_size,
                              hipStream_t stream)
{
    const float* x        = (const float*)d_in[0];
    // d_in[1] = x_len: constant 1664 -> enc_len = 208 = S (mask is a no-op)
    const int*   y        = (const int*)d_in[2];
    const float* e_fw_Wih = (const float*)d_in[3];
    const float* e_fw_Whh = (const float*)d_in[4];
    const float* e_fw_b   = (const float*)d_in[5];
    const float* e_bw_Wih = (const float*)d_in[6];
    const float* e_bw_Whh = (const float*)d_in[7];
    const float* e_bw_b   = (const float*)d_in[8];
    const float* p_fw_Wih = (const float*)d_in[9];
    const float* p_fw_Whh = (const float*)d_in[10];
    const float* p_fw_b   = (const float*)d_in[11];
    const float* p_bw_Wih = (const float*)d_in[12];
    const float* p_bw_Whh = (const float*)d_in[13];
    const float* p_bw_b   = (const float*)d_in[14];
    const float* Wk       = (const float*)d_in[15];
    const float* bk       = (const float*)d_in[16];
    const float* Wv       = (const float*)d_in[17];
    const float* bv       = (const float*)d_in[18];
    const float* emb      = (const float*)d_in[19];
    const float* d1_Wih   = (const float*)d_in[20];
    const float* d1_Whh   = (const float*)d_in[21];
    const float* d1_b     = (const float*)d_in[22];
    const float* d2_Wih   = (const float*)d_in[23];
    const float* d2_Whh   = (const float*)d_in[24];
    const float* d2_b     = (const float*)d_in[25];
    const float* b_out    = (const float*)d_in[26];

    char* base = (char*)d_ws;
    size_t off = 0;
    auto alloc = [&](size_t bytes) -> void* {
        void* p = base + off;
        off = (off + bytes + 255) & ~(size_t)255;
        return p;
    };

    // misc (both plans)
    float*    KEY = (float*)alloc(851968ull * 4);
    float*    VAL = (float*)alloc(851968ull * 4);
    float*    TBL = (float*)alloc(61440ull * 4);
    float*    HB  = (float*)alloc(32768ull * 4);
    unsigned* FLG = (unsigned*)alloc(2 * 128 * FLAG_STRIDE * 4);
    float*    H1  = (float*)alloc(32768ull * 4);
    float*    H2  = (float*)alloc(8192ull * 4);
    float*    CTX = (float*)alloc(8192ull * 4);
    float*    WT5 = (float*)alloc(720896ull * 4);  // l0 split-4 k-major weights

    const size_t A_elems = 32ull * 1664 * 512;  // 27,262,976
    const size_t B_elems = 32ull * 832 * 512;   // 13,631,488
    const size_t L3_elems = 32ull * 208 * 512;  //  3,407,872

    size_t misc_end = off;
    size_t need_f32  = misc_end + (A_elems + B_elems) * 4 + 2048;
    size_t need_bf16 = misc_end + L3_elems * 4 + (A_elems + B_elems) * 2 + 2048;

    const float* enc_out;  // fp32 [6656][512] view of final encoder output
    if (ws_size >= need_f32) {
        float* A = (float*)alloc(A_elems * 4);
        float* B = (float*)alloc(B_elems * 4);
        run_encoder<float>(x, e_fw_Wih, e_fw_Whh, e_fw_b, e_bw_Wih, e_bw_Whh, e_bw_b,
                           p_fw_Wih, p_fw_Whh, p_fw_b, p_bw_Wih, p_bw_Whh, p_bw_b,
                           A, B, HB, FLG, WT5, stream);
        enc_out = B;
    } else if (ws_size >= need_bf16) {
        float* CONV = (float*)alloc(L3_elems * 4);
        __hip_bfloat16* A = (__hip_bfloat16*)alloc(A_elems * 2);
        __hip_bfloat16* B = (__hip_bfloat16*)alloc(B_elems * 2);
        run_encoder<__hip_bfloat16>(x, e_fw_Wih, e_fw_Whh, e_fw_b, e_bw_Wih, e_bw_Whh, e_bw_b,
                                    p_fw_Wih, p_fw_Whh, p_fw_b, p_bw_Wih, p_bw_Whh, p_bw_b,
                                    A, B, HB, FLG, WT5, stream);
        hipLaunchKernelGGL(bf16_to_f32, dim3((unsigned)(L3_elems / 256)), dim3(256), 0, stream,
                           B, CONV, (int)L3_elems);
        enc_out = CONV;
    } else {
        return;  // workspace too small for any plan
    }

    // ---- key / val projections + decoder precompute ----
    hipLaunchKernelGGL(gemm_bt, dim3(52, 1), dim3(256), 0, stream,
                       enc_out, Wk, bk, KEY, 6656, 128, 512, 512);
    hipLaunchKernelGGL(gemm_bt, dim3(52, 1), dim3(256), 0, stream,
                       enc_out, Wv, bv, VAL, 6656, 128, 512, 512);
    hipLaunchKernelGGL(gemm_bt, dim3(1, 16), dim3(256), 0, stream,
                       emb, d1_Wih, d1_b, TBL, 30, 2048, 256, 384);
    hipLaunchKernelGGL(ctx0_kernel, dim3(16), dim3(256), 0, stream, VAL, CTX);
    hipMemsetAsync(H1, 0, 32768 * 4, stream);
    hipMemsetAsync(H2, 0, 8192 * 4, stream);
    hipMemsetAsync(FLG, 0, 2 * 128 * FLAG_STRIDE * 4, stream);

    float* preds = (float*)d_out;
    float* attn0 = (float*)d_out + 192000;

    // ---- fused persistent decoder: 1 launch, 200 steps ----
    hipLaunchKernelGGL(dec_fused, dim3(112), dim3(256), 0, stream,
                       TBL, y, d1_Wih, d1_Whh, d2_Wih, d2_Whh, d2_b,
                       KEY, VAL, emb, b_out, H1, H2, CTX, preds, attn0, FLG);
}